// Round 5
// baseline (140.445 us; speedup 1.0000x reference)
//
#include <hip/hip_runtime.h>
#include <math.h>

#define SD 10
#define MD 9

typedef short bf8 __attribute__((ext_vector_type(8)));
typedef float f32x4 __attribute__((ext_vector_type(4)));

__device__ inline ushort f2b(float f) {
    union { float f; unsigned u; } v; v.f = f;
    unsigned r = v.u + 0x7FFF + ((v.u >> 16) & 1);
    return (ushort)(r >> 16);
}

// ---------------- constant gh precompute (h0 is batch-constant) ----------------
__global__ void gh_precompute(const float* __restrict__ Q_Whh, const float* __restrict__ Q_bhh,
                              const float* __restrict__ R_Whh, const float* __restrict__ R_bhh,
                              const float* __restrict__ S_Whh, const float* __restrict__ S_bhh,
                              float* __restrict__ gh) {
    int j = threadIdx.x;
    if (j < 300) {
        float s = Q_bhh[j];
        #pragma unroll
        for (int i = 0; i < 10; ++i) s += Q_Whh[j * 100 + 11 * i];
        gh[j] = s;
    }
    if (j < 243) {
        float s = R_bhh[j];
        #pragma unroll
        for (int i = 0; i < 9; ++i) s += R_Whh[j * 81 + 10 * i];
        gh[320 + j] = s;
        float s2 = S_bhh[j];
        #pragma unroll
        for (int i = 0; i < 9; ++i) s2 += S_Whh[j * 81 + 10 * i];
        gh[576 + j] = s2;
    }
}

// ---------------- all small weights -> bf16 zero-padded [Npad][Kpad] ----------------
#define WBF_TOTAL 207872
#define W5O 0
#define W6O 2048
#define W7O 4096
#define W8O 5632
#define WQO 7168
#define WSIGO 26624
#define WRO 75264
#define WSO 91648
#define WFC1O 148992
#define WFC3O 161280
#define WFC4O 182784
__global__ void prep_wbf(const float* __restrict__ w5, const float* __restrict__ w6,
                         const float* __restrict__ w7, const float* __restrict__ w8,
                         const float* __restrict__ wq, const float* __restrict__ wsig,
                         const float* __restrict__ wr, const float* __restrict__ wss,
                         const float* __restrict__ w1, const float* __restrict__ w3,
                         const float* __restrict__ w4, ushort* __restrict__ dst) {
    int idx = blockIdx.x * 256 + threadIdx.x;
    if (idx >= WBF_TOTAL) return;
    const int offs[12] = {W5O, W6O, W7O, W8O, WQO, WSIGO, WRO, WSO, WFC1O, WFC3O, WFC4O, WBF_TOTAL};
    const int Ns[11]  = {50, 50, 45, 45, 300, 300, 243, 243, 81, 100, 100};
    const int Ks[11]  = {10, 10, 9, 9, 50, 150, 45, 207, 100, 171, 200};
    const int KPs[11] = {32, 32, 32, 32, 64, 160, 64, 224, 128, 192, 224};
    const float* srcs[11] = {w5, w6, w7, w8, wq, wsig, wr, wss, w1, w3, w4};
    int s = 0;
    for (int i = 1; i < 11; ++i) if (idx >= offs[i]) s = i;
    int loc = idx - offs[s];
    int r = loc / KPs[s], k = loc - r * KPs[s];
    float v = (r < Ns[s] && k < Ks[s]) ? srcs[s][(size_t)r * Ks[s] + k] : 0.f;
    dst[idx] = f2b(v);
}

// ---------------- weight converts for FC2 MFMA ----------------
__global__ void convert_w1(const float* __restrict__ W1, ushort* __restrict__ W1b) {
    int idx = blockIdx.x * 256 + threadIdx.x;
    if (idx >= 7296 * 24) return;
    int r = idx / 24, p = idx - r * 24;
    int cs = p ^ (r & 7);
    union { ushort u[8]; uint4 v; } o;
    #pragma unroll
    for (int j = 0; j < 8; ++j) {
        int k = cs * 8 + j;
        float val = (r < 7240 && k < 181) ? W1[(size_t)r * 181 + k] : 0.f;
        o.u[j] = f2b(val);
    }
    *(uint4*)(W1b + (size_t)r * 192 + p * 8) = o.v;
}

__global__ void convert_w2(const float* __restrict__ W2, ushort* __restrict__ W2b) {
    int idx = blockIdx.x * 256 + threadIdx.x;
    if (idx >= 96 * 912) return;
    int r = idx / 912, p = idx - r * 912;
    union { ushort u[8]; uint4 v; } o;
    #pragma unroll
    for (int j = 0; j < 8; ++j) {
        int k = p * 8 + j;
        float val = (r < 90 && k < 7240) ? W2[(size_t)r * 7240 + k] : 0.f;
        o.u[j] = f2b(val);
    }
    *(uint4*)(W2b + (size_t)r * 7296 + p * 8) = o.v;
}

// ---------------- generic MFMA layer ----------------
template <int KSTEPS, int MODE>
__device__ __forceinline__ void mfma_layer(
    const ushort* sX, int strideX,
    const ushort* __restrict__ Wb, int Kpad, int ntiles,
    const float* __restrict__ bias, int N,
    int w, int lr, int lk,
    float* sGi, int ldg,
    ushort* sDst, int strideD, int dcol,
    float* gDst, int gld, int row0) {
    bf8 a[KSTEPS];
    #pragma unroll
    for (int ks = 0; ks < KSTEPS; ++ks)
        a[ks] = *(const bf8*)(sX + lr * strideX + ks * 32 + lk * 8);
    for (int nt = w; nt < ntiles; nt += 4) {
        f32x4 acc = (f32x4){0.f, 0.f, 0.f, 0.f};
        #pragma unroll
        for (int ks = 0; ks < KSTEPS; ++ks) {
            bf8 Bf = *(const bf8*)(Wb + (size_t)(nt * 16 + lr) * Kpad + ks * 32 + lk * 8);
            acc = __builtin_amdgcn_mfma_f32_16x16x32_bf16(a[ks], Bf, acc, 0, 0, 0);
        }
        int n = nt * 16 + lr;
        if (n < N) {
            float b = bias[n];
            #pragma unroll
            for (int q = 0; q < 4; ++q) {
                float v = acc[q] + b;
                int m = lk * 4 + q;
                if (MODE == 0) {
                    sGi[m * ldg + n] = v;
                } else if (MODE == 1) {
                    v = fmaxf(v, 0.f);
                    sDst[m * strideD + dcol + n] = f2b(v);
                } else {
                    v = fmaxf(v, 0.f);
                    gDst[(size_t)(row0 + m) * gld + n] = v;
                }
            }
        }
    }
}

// ---------------- fused chain via MFMA (unchanged) ----------------
#define U_NORM  0
#define U_OUT5  2176
#define U_INSIG 3328
#define U_OUT8  6016
#define U_INS   7168
#define U_HSIG  10880
#define U_TOT   13056
__global__ __launch_bounds__(256) void chain_mfma(
    const float* __restrict__ obs_diff, const float* __restrict__ obs_innov,
    const float* __restrict__ fw_evol, const float* __restrict__ fw_upd,
    const ushort* __restrict__ wbf, const float* __restrict__ gh,
    const float* __restrict__ Q_bih, const float* __restrict__ Sig_bih,
    const float* __restrict__ Sig_bhh,
    const float* __restrict__ R_bih, const float* __restrict__ S_bih,
    const float* __restrict__ fc1_b, const float* __restrict__ fc5_b,
    const float* __restrict__ fc6_b, const float* __restrict__ fc7_b,
    const float* __restrict__ fc8_b,
    float* __restrict__ o_hQ, float* __restrict__ o_hR, float* __restrict__ o_hS,
    float* __restrict__ hSig_g, ushort* __restrict__ Xb) {
    __shared__ __align__(16) ushort su[U_TOT];
    __shared__ __align__(16) float sGi[16 * 305];
    const int tid = threadIdx.x;
    const int w = tid >> 6, l = tid & 63, lr = l & 15, lk = l >> 4;
    const int row0 = blockIdx.x * 16;

    for (int i = tid; i < U_TOT; i += 256) su[i] = 0;
    __syncthreads();
    if (tid < 64) {
        int v = tid >> 4, r = tid & 15;
        const float* src = (v == 0) ? fw_upd : (v == 1) ? fw_evol : (v == 2) ? obs_diff : obs_innov;
        int len = (v < 2) ? 10 : 9;
        float x[10]; float s = 0.f;
        for (int k = 0; k < len; ++k) { x[k] = src[(size_t)(row0 + r) * len + k]; s += x[k] * x[k]; }
        float sc = 1.f / fmaxf(sqrtf(s), 1e-12f);
        for (int k = 0; k < len; ++k) su[U_NORM + r * 136 + v * 32 + k] = f2b(x[k] * sc);
    }
    __syncthreads();
    mfma_layer<1, 1>(su + U_NORM + 0, 136, wbf + W5O, 32, 4, fc5_b, 50, w, lr, lk,
                     nullptr, 0, su + U_OUT5, 72, 0, nullptr, 0, 0);
    mfma_layer<1, 1>(su + U_NORM + 32, 136, wbf + W6O, 32, 4, fc6_b, 50, w, lr, lk,
                     nullptr, 0, su + U_INSIG, 168, 100, nullptr, 0, 0);
    mfma_layer<1, 1>(su + U_NORM + 64, 136, wbf + W7O, 32, 3, fc7_b, 45, w, lr, lk,
                     nullptr, 0, su + U_INS, 232, 81, nullptr, 0, 0);
    mfma_layer<1, 1>(su + U_NORM + 96, 136, wbf + W8O, 32, 3, fc8_b, 45, w, lr, lk,
                     nullptr, 0, su + U_OUT8, 72, 0, nullptr, 0, 0);
    __syncthreads();
    mfma_layer<2, 0>(su + U_OUT5, 72, wbf + WQO, 64, 19, Q_bih, 300, w, lr, lk,
                     sGi, 305, nullptr, 0, 0, nullptr, 0, 0);
    __syncthreads();
    for (int i = tid; i < 16 * 100; i += 256) {
        int r = i / 100, h = i - r * 100;
        float ir = sGi[r * 305 + h], iz = sGi[r * 305 + 100 + h], in = sGi[r * 305 + 200 + h];
        float rr = 1.f / (1.f + __expf(-(ir + gh[h])));
        float zz = 1.f / (1.f + __expf(-(iz + gh[100 + h])));
        float t = in + rr * gh[200 + h];
        float nn = 1.f - 2.f / (1.f + __expf(2.f * t));
        float h0 = ((h % 11) == 0) ? 1.f : 0.f;
        float v = (1.f - zz) * nn + zz * h0;
        su[U_INSIG + r * 168 + h] = f2b(v);
        o_hQ[(size_t)(row0 + r) * 100 + h] = v;
    }
    __syncthreads();
    mfma_layer<5, 0>(su + U_INSIG, 168, wbf + WSIGO, 160, 19, Sig_bih, 300, w, lr, lk,
                     sGi, 305, nullptr, 0, 0, nullptr, 0, 0);
    __syncthreads();
    for (int i = tid; i < 16 * 100; i += 256) {
        int r = i / 100, h = i - r * 100;
        float ir = sGi[r * 305 + h], iz = sGi[r * 305 + 100 + h], in = sGi[r * 305 + 200 + h];
        float rr = 1.f / (1.f + __expf(-(ir + Sig_bhh[h])));
        float zz = 1.f / (1.f + __expf(-(iz + Sig_bhh[100 + h])));
        float t = in + rr * Sig_bhh[200 + h];
        float nn = 1.f - 2.f / (1.f + __expf(2.f * t));
        float v = (1.f - zz) * nn;
        su[U_HSIG + r * 136 + h] = f2b(v);
        hSig_g[(size_t)(row0 + r) * 100 + h] = v;
        Xb[(size_t)(row0 + r) * 192 + h] = f2b(v);
    }
    __syncthreads();
    mfma_layer<4, 1>(su + U_HSIG, 136, wbf + WFC1O, 128, 6, fc1_b, 81, w, lr, lk,
                     nullptr, 0, su + U_INS, 232, 0, nullptr, 0, 0);
    mfma_layer<2, 0>(su + U_OUT8, 72, wbf + WRO, 64, 16, R_bih, 243, w, lr, lk,
                     sGi, 305, nullptr, 0, 0, nullptr, 0, 0);
    __syncthreads();
    for (int i = tid; i < 16 * 81; i += 256) {
        int r = i / 81, h = i - r * 81;
        float ir = sGi[r * 305 + h], iz = sGi[r * 305 + 81 + h], in = sGi[r * 305 + 162 + h];
        float rr = 1.f / (1.f + __expf(-(ir + gh[320 + h])));
        float zz = 1.f / (1.f + __expf(-(iz + gh[320 + 81 + h])));
        float t = in + rr * gh[320 + 162 + h];
        float nn = 1.f - 2.f / (1.f + __expf(2.f * t));
        float h0 = ((h % 10) == 0) ? 1.f : 0.f;
        float v = (1.f - zz) * nn + zz * h0;
        su[U_INS + r * 232 + 126 + h] = f2b(v);
        o_hR[(size_t)(row0 + r) * 81 + h] = v;
    }
    __syncthreads();
    mfma_layer<7, 0>(su + U_INS, 232, wbf + WSO, 224, 16, S_bih, 243, w, lr, lk,
                     sGi, 305, nullptr, 0, 0, nullptr, 0, 0);
    __syncthreads();
    for (int i = tid; i < 16 * 81; i += 256) {
        int r = i / 81, h = i - r * 81;
        float ir = sGi[r * 305 + h], iz = sGi[r * 305 + 81 + h], in = sGi[r * 305 + 162 + h];
        float rr = 1.f / (1.f + __expf(-(ir + gh[576 + h])));
        float zz = 1.f / (1.f + __expf(-(iz + gh[576 + 81 + h])));
        float t = in + rr * gh[576 + 162 + h];
        float nn = 1.f - 2.f / (1.f + __expf(2.f * t));
        float h0 = ((h % 10) == 0) ? 1.f : 0.f;
        float v = (1.f - zz) * nn + zz * h0;
        o_hS[(size_t)(row0 + r) * 81 + h] = v;
        Xb[(size_t)(row0 + r) * 192 + 100 + h] = f2b(v);
    }
}

// ---------------- FC2 via bf16 MFMA: double-buffered staging + counted vmcnt ----------------
__global__ __launch_bounds__(256, 2) void fc2_mfma(
    const ushort* __restrict__ Xb, const ushort* __restrict__ W1b,
    const float* __restrict__ b1, const ushort* __restrict__ W2b,
    float* __restrict__ partial, int B) {
    __shared__ ushort sW1[2][64 * 192];     // 2 x 24576 B (double buffer)
    __shared__ ushort sHid[4][64 * 56];     // 28672 B, per-wave strips
    const int tid = threadIdx.x;
    const int w = tid >> 6, l = tid & 63;
    const int lr = l & 15, lk = l >> 4;
    const int bid = blockIdx.x;
    const int mt = bid >> 2, split = bid & 3;
    const int m0 = mt * 64;
    const int u0 = (57 * split) / 4, u1 = (57 * (split + 1)) / 4;
    const int NT = (u1 - u0) * 2;           // 64-row half-chunks

    // persistent A-frags: X rows m0..m0+63, K=192
    bf8 A[4][6];
    {
        const ushort* xp = Xb + (size_t)(m0 + lr) * 192 + lk * 8;
        #pragma unroll
        for (int mi = 0; mi < 4; ++mi)
            #pragma unroll
            for (int ks = 0; ks < 6; ++ks)
                A[mi][ks] = *(const bf8*)(xp + (size_t)mi * 16 * 192 + ks * 32);
    }

    f32x4 acc2[4][6];
    #pragma unroll
    for (int mi = 0; mi < 4; ++mi)
        #pragma unroll
        for (int nj = 0; nj < 6; ++nj) acc2[mi][nj] = (f32x4){0.f, 0.f, 0.f, 0.f};

    ushort* myHid = &sHid[w][0];
    const int nloc = w * 16 + lr;

    // issue staging of half-chunk t into buffer b (6 global_load_lds per wave, 24 KB total)
    auto issue = [&](int t, int b) {
        const int rbase = (u0 + (t >> 1)) * 128 + (t & 1) * 64;
        #pragma unroll
        for (int p = 0; p < 6; ++p) {
            const ushort* g = W1b + (size_t)rbase * 192 + (p * 4 + w) * 512 + l * 8;
            __builtin_amdgcn_global_load_lds(
                (const __attribute__((address_space(1))) unsigned int*)g,
                (__attribute__((address_space(3))) unsigned int*)(&sW1[b][0] + (p * 4 + w) * 512),
                16, 0, 0);
        }
    };

    issue(0, 0);
    for (int t = 0; t < NT; ++t) {
        const int cur = t & 1;
        if (t + 1 < NT) {
            issue(t + 1, cur ^ 1);
            asm volatile("s_waitcnt vmcnt(6)" ::: "memory");   // my 6 loads for buf[cur] done
        } else {
            asm volatile("s_waitcnt vmcnt(0)" ::: "memory");
        }
        __builtin_amdgcn_s_barrier();                          // all waves' staging arrived

        const int u = u0 + (t >> 1), h = t & 1;
        const int n0 = u * 128;
        // GEMM1: hid[64][16-strip] = X @ W1chunk^T
        f32x4 acc1[4];
        #pragma unroll
        for (int mi = 0; mi < 4; ++mi) acc1[mi] = (f32x4){0.f, 0.f, 0.f, 0.f};
        #pragma unroll
        for (int ks = 0; ks < 6; ++ks) {
            int cs = ks * 4 + lk;
            int p = cs ^ (nloc & 7);   // undo the pre-swizzle -> conflict-free
            bf8 Bf = *(const bf8*)(&sW1[cur][0] + nloc * 192 + p * 8);
            #pragma unroll
            for (int mi = 0; mi < 4; ++mi)
                acc1[mi] = __builtin_amdgcn_mfma_f32_16x16x32_bf16(A[mi][ks], Bf, acc1[mi], 0, 0, 0);
        }
        int gn = n0 + h * 64 + nloc;
        float bias = (gn < 7240) ? b1[gn] : 0.f;
        #pragma unroll
        for (int mi = 0; mi < 4; ++mi)
            #pragma unroll
            for (int q = 0; q < 4; ++q) {
                float v = fmaxf(acc1[mi][q] + bias, 0.f);
                myHid[(mi * 16 + lk * 4 + q) * 56 + h * 16 + lr] = f2b(v);
            }
        if (h == 1) {
            // GEMM2 on the completed 32-col strip (wave-local, no barrier needed)
            bf8 aF[4];
            #pragma unroll
            for (int mi = 0; mi < 4; ++mi)
                aF[mi] = *(const bf8*)(myHid + (mi * 16 + lr) * 56 + lk * 8);
            const size_t kbase = (size_t)n0 + (lk >> 1) * 64 + w * 16 + (lk & 1) * 8;
            #pragma unroll
            for (int nj = 0; nj < 6; ++nj) {
                bf8 Bf2 = *(const bf8*)(W2b + (size_t)(nj * 16 + lr) * 7296 + kbase);
                #pragma unroll
                for (int mi = 0; mi < 4; ++mi)
                    acc2[mi][nj] = __builtin_amdgcn_mfma_f32_16x16x32_bf16(aF[mi], Bf2, acc2[mi][nj], 0, 0, 0);
            }
        }
        __builtin_amdgcn_s_barrier();   // compute done before next issue overwrites buf[cur^1]
    }

    // cross-wave reduction
    float* red1 = (float*)&sW1[0][0];
    float* red2 = (float*)&sHid[0][0];
    __syncthreads();
    if (w == 1 || w == 3) {
        float* r_ = (w == 1) ? red1 : red2;
        #pragma unroll
        for (int mi = 0; mi < 4; ++mi)
            #pragma unroll
            for (int nj = 0; nj < 6; ++nj)
                #pragma unroll
                for (int q = 0; q < 4; ++q)
                    r_[(mi * 16 + lk * 4 + q) * 96 + nj * 16 + lr] = acc2[mi][nj][q];
    }
    __syncthreads();
    if (w == 0 || w == 2) {
        float* r_ = (w == 0) ? red1 : red2;
        #pragma unroll
        for (int mi = 0; mi < 4; ++mi)
            #pragma unroll
            for (int nj = 0; nj < 6; ++nj)
                #pragma unroll
                for (int q = 0; q < 4; ++q)
                    r_[(mi * 16 + lk * 4 + q) * 96 + nj * 16 + lr] += acc2[mi][nj][q];
    }
    __syncthreads();
    float* dst = partial + ((size_t)split * B + m0) * 96;
    for (int i = tid; i < 64 * 96; i += 256) dst[i] = red1[i] + red2[i];
}

// ---------------- fused tail: combine partials + FC3 + FC4 via MFMA ----------------
__global__ __launch_bounds__(256) void tail_mfma(
    const float* __restrict__ partial, const float* __restrict__ b2,
    const float* __restrict__ o_hS, const float* __restrict__ hSig_g,
    const ushort* __restrict__ wbf, const float* __restrict__ fc3_b,
    const float* __restrict__ fc4_b,
    float* __restrict__ o_kg, float* __restrict__ o_hSn, int B) {
    __shared__ __align__(16) ushort s3[16 * 200];
    __shared__ __align__(16) ushort s4[16 * 232];
    const int tid = threadIdx.x;
    const int w = tid >> 6, l = tid & 63, lr = l & 15, lk = l >> 4;
    const int row0 = blockIdx.x * 16;

    for (int i = tid; i < 16 * 200; i += 256) s3[i] = 0;
    for (int i = tid; i < 16 * 232; i += 256) s4[i] = 0;
    __syncthreads();
    for (int i = tid; i < 16 * 81; i += 256) {
        int r = i / 81, n = i - r * 81;
        s3[r * 200 + n] = f2b(o_hS[(size_t)(row0 + r) * 81 + n]);
    }
    for (int i = tid; i < 16 * 100; i += 256) {
        int r = i / 100, n = i - r * 100;
        s4[r * 232 + n] = f2b(hSig_g[(size_t)(row0 + r) * 100 + n]);
    }
    for (int i = tid; i < 16 * 90; i += 256) {
        int r = i / 90, n = i - r * 90;
        size_t rw = (size_t)(row0 + r);
        float v = partial[rw * 96 + n] + partial[((size_t)B + rw) * 96 + n]
                + partial[((size_t)2 * B + rw) * 96 + n] + partial[((size_t)3 * B + rw) * 96 + n]
                + b2[n];
        o_kg[rw * 90 + n] = v;
        s3[r * 200 + 81 + n] = f2b(v);
    }
    __syncthreads();
    mfma_layer<6, 1>(s3, 200, wbf + WFC3O, 192, 7, fc3_b, 100, w, lr, lk,
                     nullptr, 0, s4, 232, 100, nullptr, 0, 0);
    __syncthreads();
    mfma_layer<7, 2>(s4, 232, wbf + WFC4O, 224, 7, fc4_b, 100, w, lr, lk,
                     nullptr, 0, nullptr, 0, 0, o_hSn, 100, row0);
}

extern "C" void kernel_launch(void* const* d_in, const int* in_sizes, int n_in,
                              void* d_out, int out_size, void* d_ws, size_t ws_size,
                              hipStream_t stream) {
    const float* obs_diff  = (const float*)d_in[0];
    const float* obs_innov = (const float*)d_in[1];
    const float* fw_evol   = (const float*)d_in[2];
    const float* fw_upd    = (const float*)d_in[3];
    const float* Q_Wih  = (const float*)d_in[4];
    const float* Q_Whh  = (const float*)d_in[5];
    const float* Q_bih  = (const float*)d_in[6];
    const float* Q_bhh  = (const float*)d_in[7];
    const float* Sig_Wih = (const float*)d_in[8];
    const float* Sig_bih = (const float*)d_in[10];
    const float* Sig_bhh = (const float*)d_in[11];
    const float* S_Wih  = (const float*)d_in[12];
    const float* S_Whh  = (const float*)d_in[13];
    const float* S_bih  = (const float*)d_in[14];
    const float* S_bhh  = (const float*)d_in[15];
    const float* R_Wih  = (const float*)d_in[16];
    const float* R_Whh  = (const float*)d_in[17];
    const float* R_bih  = (const float*)d_in[18];
    const float* R_bhh  = (const float*)d_in[19];
    const float* fc1_W = (const float*)d_in[20];
    const float* fc1_b = (const float*)d_in[21];
    const float* fc2_W1 = (const float*)d_in[22];
    const float* fc2_b1 = (const float*)d_in[23];
    const float* fc2_W2 = (const float*)d_in[24];
    const float* fc2_b2 = (const float*)d_in[25];
    const float* fc3_W = (const float*)d_in[26];
    const float* fc3_b = (const float*)d_in[27];
    const float* fc4_W = (const float*)d_in[28];
    const float* fc4_b = (const float*)d_in[29];
    const float* fc5_W = (const float*)d_in[30];
    const float* fc5_b = (const float*)d_in[31];
    const float* fc6_W = (const float*)d_in[32];
    const float* fc6_b = (const float*)d_in[33];
    const float* fc7_W = (const float*)d_in[34];
    const float* fc7_b = (const float*)d_in[35];
    const float* fc8_W = (const float*)d_in[36];
    const float* fc8_b = (const float*)d_in[37];

    const int B = in_sizes[0] / MD;   // 8192
    float* ws = (float*)d_ws;
    float* gh = ws;
    size_t off = 1024;
    ushort* wbf = (ushort*)(ws + off); off += WBF_TOTAL / 2;
    float* hSig_g = ws + off; off += (size_t)B * 100;
    ushort* Xb   = (ushort*)(ws + off); off += (size_t)B * 96;
    ushort* W1b  = (ushort*)(ws + off); off += 700416;
    ushort* W2b  = (ushort*)(ws + off); off += 350208;
    float* part  = ws + off; off += (size_t)4 * B * 96;

    float* out = (float*)d_out;
    float* o_kg  = out;
    float* o_hS  = out + (size_t)B * 90;
    float* o_hSn = out + (size_t)B * 171;
    float* o_hQ  = out + (size_t)B * 271;
    float* o_hR  = out + (size_t)B * 371;

    hipLaunchKernelGGL(gh_precompute, dim3(1), dim3(512), 0, stream,
                       Q_Whh, Q_bhh, R_Whh, R_bhh, S_Whh, S_bhh, gh);
    hipLaunchKernelGGL(prep_wbf, dim3((WBF_TOTAL + 255) / 256), dim3(256), 0, stream,
                       fc5_W, fc6_W, fc7_W, fc8_W, Q_Wih, Sig_Wih, R_Wih, S_Wih,
                       fc1_W, fc3_W, fc4_W, wbf);
    hipLaunchKernelGGL(convert_w1, dim3((7296 * 24 + 255) / 256), dim3(256), 0, stream, fc2_W1, W1b);
    hipLaunchKernelGGL(convert_w2, dim3((96 * 912 + 255) / 256), dim3(256), 0, stream, fc2_W2, W2b);
    hipLaunchKernelGGL(chain_mfma, dim3(B / 16), dim3(256), 0, stream,
                       obs_diff, obs_innov, fw_evol, fw_upd,
                       wbf, gh, Q_bih, Sig_bih, Sig_bhh, R_bih, S_bih,
                       fc1_b, fc5_b, fc6_b, fc7_b, fc8_b,
                       o_hQ, o_hR, o_hS, hSig_g, Xb);
    hipLaunchKernelGGL(fc2_mfma, dim3((B / 64) * 4), dim3(256), 0, stream,
                       Xb, W1b, fc2_b1, W2b, part, B);
    hipLaunchKernelGGL(tail_mfma, dim3(B / 16), dim3(256), 0, stream,
                       part, fc2_b2, o_hS, hSig_g, wbf, fc3_b, fc4_b,
                       o_kg, o_hSn, B);
}